// Round 1
// baseline (876.620 us; speedup 1.0000x reference)
//
#include <hip/hip_runtime.h>
#include <math.h>

#define SLOPE 0.2f

// ---------------------------------------------------------------- init ----
__global__ __launch_bounds__(256) void init_kernel(float* __restrict__ agg,
                                                   float* __restrict__ m,
                                                   float* __restrict__ denom,
                                                   int n) {
    int i = blockIdx.x * 256 + threadIdx.x;
    int total = n * 64;
    if (i < total) agg[i] = 0.0f;
    if (i < n) { m[i] = -INFINITY; denom[i] = 0.0f; }
}

// ---------------------------------------------------------------- gemm ----
// z[node][o] = sum_k h[node][k] * W[o][k];  h:[n][128], W:[64][128], z:[n][64]
// One thread per node; h row held in 32 float4 registers; W accesses are
// wave-uniform -> compiler emits scalar loads (SGPR operand into v_fma).
__global__ __launch_bounds__(256) void gemm_kernel(const float* __restrict__ h,
                                                   const float* __restrict__ W,
                                                   float* __restrict__ z, int n) {
    int node = blockIdx.x * 256 + threadIdx.x;
    if (node >= n) return;
    const float4* __restrict__ h4 = reinterpret_cast<const float4*>(h) + (size_t)node * 32;
    float4 hr[32];
#pragma unroll
    for (int i = 0; i < 32; i++) hr[i] = h4[i];
    const float4* __restrict__ W4 = reinterpret_cast<const float4*>(W);
    float4* __restrict__ z4 = reinterpret_cast<float4*>(z) + (size_t)node * 16;
    for (int og = 0; og < 16; og++) {
        float a0 = 0.f, a1 = 0.f, a2 = 0.f, a3 = 0.f;
#pragma unroll
        for (int i = 0; i < 32; i++) {
            float4 hv = hr[i];
            float4 w;
            w = W4[(og * 4 + 0) * 32 + i]; a0 += hv.x * w.x + hv.y * w.y + hv.z * w.z + hv.w * w.w;
            w = W4[(og * 4 + 1) * 32 + i]; a1 += hv.x * w.x + hv.y * w.y + hv.z * w.z + hv.w * w.w;
            w = W4[(og * 4 + 2) * 32 + i]; a2 += hv.x * w.x + hv.y * w.y + hv.z * w.z + hv.w * w.w;
            w = W4[(og * 4 + 3) * 32 + i]; a3 += hv.x * w.x + hv.y * w.y + hv.z * w.z + hv.w * w.w;
        }
        z4[og] = make_float4(a0, a1, a2, a3);
    }
}

// ------------------------------------------------------------ edge dot ----
// e[i] = leaky_relu(dot(z[src], z[dst])); segment max into m via float-as-int
// atomic trick (m initialized to -inf).
__global__ __launch_bounds__(256) void edge_dot_kernel(const float* __restrict__ z,
                                                       const int* __restrict__ src,
                                                       const int* __restrict__ dst,
                                                       float* __restrict__ e,
                                                       float* __restrict__ m, int ne) {
    int i = blockIdx.x * 256 + threadIdx.x;
    if (i >= ne) return;
    int s = src[i], d = dst[i];
    const float4* __restrict__ zs = reinterpret_cast<const float4*>(z) + (size_t)s * 16;
    const float4* __restrict__ zd = reinterpret_cast<const float4*>(z) + (size_t)d * 16;
    float acc = 0.f;
#pragma unroll
    for (int k = 0; k < 16; k++) {
        float4 a = zs[k], b = zd[k];
        acc += a.x * b.x + a.y * b.y + a.z * b.z + a.w * b.w;
    }
    float ev = acc > 0.f ? acc : SLOPE * acc;
    ev += 0.0f;                 // canonicalize -0.0 -> +0.0 for the bit-trick
    e[i] = ev;
    if (ev >= 0.f) atomicMax(reinterpret_cast<int*>(m + d), __float_as_int(ev));
    else           atomicMin(reinterpret_cast<unsigned int*>(m + d), __float_as_uint(ev));
}

// ----------------------------------------------------------- aggregate ----
// One wave per edge; lane = output channel. Accumulates ex*z_src into agg
// and ex into denom (lane 0). Normalization deferred to final pass.
__global__ __launch_bounds__(256) void agg_kernel(const float* __restrict__ z,
                                                  const int* __restrict__ src,
                                                  const int* __restrict__ dst,
                                                  const float* __restrict__ e,
                                                  const float* __restrict__ m,
                                                  float* __restrict__ denom,
                                                  float* __restrict__ agg, int ne) {
    int edge = blockIdx.x * 4 + (threadIdx.x >> 6);
    if (edge >= ne) return;
    int lane = threadIdx.x & 63;
    int s = src[edge], d = dst[edge];
    float ex = __expf(e[edge] - m[d]);
    float v = z[(size_t)s * 64 + lane];
    atomicAdd(agg + (size_t)d * 64 + lane, ex * v);
    if (lane == 0) atomicAdd(denom + d, ex);
}

// ------------------------------------------------------------ finalize ----
__global__ __launch_bounds__(256) void final_kernel(float* __restrict__ out,
                                                    const float* __restrict__ denom,
                                                    int n) {
    int i = blockIdx.x * 256 + threadIdx.x;
    if (i >= n * 64) return;
    float dn = denom[i >> 6];
    float x = dn > 0.f ? out[i] / dn : 0.f;
    out[i] = x > 0.f ? x : expm1f(x);
}

// -------------------------------------------------------------- launch ----
extern "C" void kernel_launch(void* const* d_in, const int* in_sizes, int n_in,
                              void* d_out, int out_size, void* d_ws, size_t ws_size,
                              hipStream_t stream) {
    const float* h   = (const float*)d_in[0];
    const float* W   = (const float*)d_in[1];
    const int*   src = (const int*)d_in[2];
    const int*   dst = (const int*)d_in[3];
    int n  = in_sizes[0] / 128;   // 100000
    int ne = in_sizes[2];         // 1600000
    float* out = (float*)d_out;

    float* z     = (float*)d_ws;            // n*64 floats (25.6 MB)
    float* e     = z + (size_t)n * 64;      // ne floats   (6.4 MB)
    float* m     = e + ne;                  // n floats
    float* denom = m + n;                   // n floats

    init_kernel<<<(n * 64 + 255) / 256, 256, 0, stream>>>(out, m, denom, n);
    gemm_kernel<<<(n + 255) / 256, 256, 0, stream>>>(h, W, z, n);
    edge_dot_kernel<<<(ne + 255) / 256, 256, 0, stream>>>(z, src, dst, e, m, ne);
    agg_kernel<<<(ne + 3) / 4, 256, 0, stream>>>(z, src, dst, e, m, denom, out, ne);
    final_kernel<<<(n * 64 + 255) / 256, 256, 0, stream>>>(out, denom, n);
}

// Round 4
// 682.017 us; speedup vs baseline: 1.2853x; 1.2853x over previous
//
#include <hip/hip_runtime.h>
#include <math.h>

#define SLOPE 0.2f

// --------------------------------------------------------------- zero ----
__global__ __launch_bounds__(256) void zero_cnt(int* __restrict__ cnt, int n) {
    int i = blockIdx.x * 256 + threadIdx.x;
    if (i < n) cnt[i] = 0;
}

// ---------------------------------------------------------------- gemm ----
// z[node][o] = sum_k h[node][k] * W[o][k];  h:[n][128], W:[64][128], z:[n][64]
__global__ __launch_bounds__(256) void gemm_kernel(const float* __restrict__ h,
                                                   const float* __restrict__ W,
                                                   float* __restrict__ z, int n) {
    int node = blockIdx.x * 256 + threadIdx.x;
    if (node >= n) return;
    const float4* __restrict__ h4 = reinterpret_cast<const float4*>(h) + (size_t)node * 32;
    float4 hr[32];
#pragma unroll
    for (int i = 0; i < 32; i++) hr[i] = h4[i];
    const float4* __restrict__ W4 = reinterpret_cast<const float4*>(W);
    float4* __restrict__ z4 = reinterpret_cast<float4*>(z) + (size_t)node * 16;
    for (int og = 0; og < 16; og++) {
        float a0 = 0.f, a1 = 0.f, a2 = 0.f, a3 = 0.f;
#pragma unroll
        for (int i = 0; i < 32; i++) {
            float4 hv = hr[i];
            float4 w;
            w = W4[(og * 4 + 0) * 32 + i]; a0 += hv.x * w.x + hv.y * w.y + hv.z * w.z + hv.w * w.w;
            w = W4[(og * 4 + 1) * 32 + i]; a1 += hv.x * w.x + hv.y * w.y + hv.z * w.z + hv.w * w.w;
            w = W4[(og * 4 + 2) * 32 + i]; a2 += hv.x * w.x + hv.y * w.y + hv.z * w.z + hv.w * w.w;
            w = W4[(og * 4 + 3) * 32 + i]; a3 += hv.x * w.x + hv.y * w.y + hv.z * w.z + hv.w * w.w;
        }
        z4[og] = make_float4(a0, a1, a2, a3);
    }
}

// ---------------------------------------------------------- histogram ----
__global__ __launch_bounds__(256) void hist_kernel(const int* __restrict__ dst,
                                                   int* __restrict__ cnt, int ne) {
    int i = blockIdx.x * 256 + threadIdx.x;
    if (i < ne) atomicAdd(&cnt[dst[i]], 1);
}

// ------------------------------------------------- scan (4096/block) -----
__global__ __launch_bounds__(256) void scan1(const int* __restrict__ cnt,
                                             int* __restrict__ starts,
                                             int* __restrict__ bsums, int n) {
    __shared__ int ls[256];
    int tbase = blockIdx.x * 4096 + threadIdx.x * 16;
    int v[16];
    int s = 0;
#pragma unroll
    for (int k = 0; k < 16; k++) {
        int idx = tbase + k;
        int c = idx < n ? cnt[idx] : 0;
        v[k] = c; s += c;
    }
    ls[threadIdx.x] = s;
    __syncthreads();
    for (int off = 1; off < 256; off <<= 1) {
        int t = threadIdx.x >= off ? ls[threadIdx.x - off] : 0;
        __syncthreads();
        ls[threadIdx.x] += t;
        __syncthreads();
    }
    int run = ls[threadIdx.x] - s;   // exclusive prefix of this thread
    if (threadIdx.x == 255) bsums[blockIdx.x] = ls[255];
#pragma unroll
    for (int k = 0; k < 16; k++) {
        int idx = tbase + k;
        if (idx < n) starts[idx] = run;
        run += v[k];
    }
}

__global__ void scan2(int* __restrict__ bsums, int nb, int* __restrict__ starts,
                      int n, int ne) {
    if (threadIdx.x == 0) {
        int run = 0;
        for (int b = 0; b < nb; b++) { int t = bsums[b]; bsums[b] = run; run += t; }
        starts[n] = ne;
    }
}

__global__ __launch_bounds__(256) void scan3(int* __restrict__ starts,
                                             int* __restrict__ cursor,
                                             const int* __restrict__ bsums, int n) {
    int i = blockIdx.x * 256 + threadIdx.x;
    if (i < n) {
        int v = starts[i] + bsums[i >> 12];
        starts[i] = v;
        cursor[i] = v;
    }
}

// --------------------------------- edge dot + scatter into CSR order -----
__global__ __launch_bounds__(256) void edge_dot_scatter(const float* __restrict__ z,
                                                        const int* __restrict__ src,
                                                        const int* __restrict__ dst,
                                                        int* __restrict__ cursor,
                                                        int* __restrict__ csr_src,
                                                        float* __restrict__ csr_e, int ne) {
    int i = blockIdx.x * 256 + threadIdx.x;
    if (i >= ne) return;
    int s = src[i], d = dst[i];
    const float4* __restrict__ zs = reinterpret_cast<const float4*>(z) + (size_t)s * 16;
    const float4* __restrict__ zd = reinterpret_cast<const float4*>(z) + (size_t)d * 16;
    float acc = 0.f;
#pragma unroll
    for (int k = 0; k < 16; k++) {
        float4 a = zs[k], b = zd[k];
        acc += a.x * b.x + a.y * b.y + a.z * b.z + a.w * b.w;
    }
    float ev = acc > 0.f ? acc : SLOPE * acc;
    int pos = atomicAdd(&cursor[d], 1);
    csr_src[pos] = s;
    csr_e[pos]   = ev;
}

// ----------------------- per-node softmax + aggregation + elu (no atomics)
// One wave per node; lane = output channel. Edges of the node are contiguous
// in [starts[v], starts[v+1]). Chunk 64 edges into lane registers, broadcast
// via shuffle; exp computed once per edge.
__global__ __launch_bounds__(256) void node_agg(const float* __restrict__ z,
                                                const int* __restrict__ starts,
                                                const int* __restrict__ csr_src,
                                                const float* __restrict__ csr_e,
                                                float* __restrict__ out, int n) {
    int node = blockIdx.x * 4 + (threadIdx.x >> 6);
    if (node >= n) return;
    int lane = threadIdx.x & 63;
    int rs = starts[node], re = starts[node + 1];

    // pass 1: segment max
    float m = -INFINITY;
    for (int c = rs; c < re; c += 64) {
        int j = c + lane;
        float ev = j < re ? csr_e[j] : -INFINITY;
        m = fmaxf(m, ev);
    }
#pragma unroll
    for (int mask = 32; mask; mask >>= 1) m = fmaxf(m, __shfl_xor(m, mask));

    // pass 2: weighted aggregation
    float acc = 0.f, denom = 0.f;
    for (int c = rs; c < re; c += 64) {
        int j = c + lane;
        int cn = min(64, re - c);
        float ex_l = j < re ? __expf(csr_e[j] - m) : 0.f;
        int   sv   = j < re ? csr_src[j] : 0;
        for (int k = 0; k < cn; k++) {
            float ex = __shfl(ex_l, k);
            int   s  = __shfl(sv, k);
            acc += ex * z[(size_t)s * 64 + lane];
        }
        denom += ex_l;
    }
#pragma unroll
    for (int mask = 32; mask; mask >>= 1) denom += __shfl_xor(denom, mask);

    float x = denom > 0.f ? acc / denom : 0.f;
    out[(size_t)node * 64 + lane] = x > 0.f ? x : expm1f(x);
}

// -------------------------------------------------------------- launch ----
extern "C" void kernel_launch(void* const* d_in, const int* in_sizes, int n_in,
                              void* d_out, int out_size, void* d_ws, size_t ws_size,
                              hipStream_t stream) {
    const float* h   = (const float*)d_in[0];
    const float* W   = (const float*)d_in[1];
    const int*   src = (const int*)d_in[2];
    const int*   dst = (const int*)d_in[3];
    int n  = in_sizes[0] / 128;   // 100000
    int ne = in_sizes[2];         // 1600000
    float* out = (float*)d_out;

    float* z       = (float*)d_ws;                    // n*64 floats
    int*   starts  = (int*)(z + (size_t)n * 64);      // n+1 ints
    int*   cursor  = starts + (n + 1);                // n ints (also histogram)
    int*   csr_src = cursor + n;                      // ne ints
    float* csr_e   = (float*)(csr_src + ne);          // ne floats
    int*   bsums   = (int*)(csr_e + ne);              // 32 ints

    int nb_scan = (n + 4095) / 4096;                  // 25

    zero_cnt<<<(n + 255) / 256, 256, 0, stream>>>(cursor, n);
    gemm_kernel<<<(n + 255) / 256, 256, 0, stream>>>(h, W, z, n);
    hist_kernel<<<(ne + 255) / 256, 256, 0, stream>>>(dst, cursor, ne);
    scan1<<<nb_scan, 256, 0, stream>>>(cursor, starts, bsums, n);
    scan2<<<1, 64, 0, stream>>>(bsums, nb_scan, starts, n, ne);
    scan3<<<(n + 255) / 256, 256, 0, stream>>>(starts, cursor, bsums, n);
    edge_dot_scatter<<<(ne + 255) / 256, 256, 0, stream>>>(z, src, dst, cursor,
                                                           csr_src, csr_e, ne);
    node_agg<<<(n + 3) / 4, 256, 0, stream>>>(z, starts, csr_src, csr_e, out, n);
}

// Round 6
// 486.056 us; speedup vs baseline: 1.8035x; 1.4032x over previous
//
#include <hip/hip_runtime.h>
#include <math.h>

#define SLOPE 0.2f

// --------------------------------------------------------------- zero ----
__global__ __launch_bounds__(256) void zero_cnt(int* __restrict__ cnt, int n) {
    int i = blockIdx.x * 256 + threadIdx.x;
    if (i < n) cnt[i] = 0;
}

// ---------------------------------------------------------------- gemm ----
// z[node][o] = sum_k h[node][k] * W[o][k];  h:[n][128], W:[64][128], z:[n][64]
__global__ __launch_bounds__(256) void gemm_kernel(const float* __restrict__ h,
                                                   const float* __restrict__ W,
                                                   float* __restrict__ z, int n) {
    int node = blockIdx.x * 256 + threadIdx.x;
    if (node >= n) return;
    const float4* __restrict__ h4 = reinterpret_cast<const float4*>(h) + (size_t)node * 32;
    float4 hr[32];
#pragma unroll
    for (int i = 0; i < 32; i++) hr[i] = h4[i];
    const float4* __restrict__ W4 = reinterpret_cast<const float4*>(W);
    float4* __restrict__ z4 = reinterpret_cast<float4*>(z) + (size_t)node * 16;
    for (int og = 0; og < 16; og++) {
        float a0 = 0.f, a1 = 0.f, a2 = 0.f, a3 = 0.f;
#pragma unroll
        for (int i = 0; i < 32; i++) {
            float4 hv = hr[i];
            float4 w;
            w = W4[(og * 4 + 0) * 32 + i]; a0 += hv.x * w.x + hv.y * w.y + hv.z * w.z + hv.w * w.w;
            w = W4[(og * 4 + 1) * 32 + i]; a1 += hv.x * w.x + hv.y * w.y + hv.z * w.z + hv.w * w.w;
            w = W4[(og * 4 + 2) * 32 + i]; a2 += hv.x * w.x + hv.y * w.y + hv.z * w.z + hv.w * w.w;
            w = W4[(og * 4 + 3) * 32 + i]; a3 += hv.x * w.x + hv.y * w.y + hv.z * w.z + hv.w * w.w;
        }
        z4[og] = make_float4(a0, a1, a2, a3);
    }
}

// ---------------------------------------------------------- histogram ----
__global__ __launch_bounds__(256) void hist_kernel(const int* __restrict__ dst,
                                                   int* __restrict__ cnt, int ne) {
    int i = blockIdx.x * 256 + threadIdx.x;
    if (i < ne) atomicAdd(&cnt[dst[i]], 1);
}

// ------------------------------------------------- scan (4096/block) -----
__global__ __launch_bounds__(256) void scan1(const int* __restrict__ cnt,
                                             int* __restrict__ starts,
                                             int* __restrict__ bsums, int n) {
    __shared__ int ls[256];
    int tbase = blockIdx.x * 4096 + threadIdx.x * 16;
    int v[16];
    int s = 0;
#pragma unroll
    for (int k = 0; k < 16; k++) {
        int idx = tbase + k;
        int c = idx < n ? cnt[idx] : 0;
        v[k] = c; s += c;
    }
    ls[threadIdx.x] = s;
    __syncthreads();
    for (int off = 1; off < 256; off <<= 1) {
        int t = threadIdx.x >= off ? ls[threadIdx.x - off] : 0;
        __syncthreads();
        ls[threadIdx.x] += t;
        __syncthreads();
    }
    int run = ls[threadIdx.x] - s;   // exclusive prefix of this thread
    if (threadIdx.x == 255) bsums[blockIdx.x] = ls[255];
#pragma unroll
    for (int k = 0; k < 16; k++) {
        int idx = tbase + k;
        if (idx < n) starts[idx] = run;
        run += v[k];
    }
}

__global__ void scan2(int* __restrict__ bsums, int nb, int* __restrict__ starts,
                      int n, int ne) {
    if (threadIdx.x == 0) {
        int run = 0;
        for (int b = 0; b < nb; b++) { int t = bsums[b]; bsums[b] = run; run += t; }
        starts[n] = ne;
    }
}

__global__ __launch_bounds__(256) void scan3(int* __restrict__ starts,
                                             int* __restrict__ cursor,
                                             const int* __restrict__ bsums, int n) {
    int i = blockIdx.x * 256 + threadIdx.x;
    if (i < n) {
        int v = starts[i] + bsums[i >> 12];
        starts[i] = v;
        cursor[i] = v;
    }
}

// -------------------------------------- scatter src indices into CSR -----
__global__ __launch_bounds__(256) void scatter_kernel(const int* __restrict__ src,
                                                      const int* __restrict__ dst,
                                                      int* __restrict__ cursor,
                                                      int* __restrict__ csr_src, int ne) {
    int i = blockIdx.x * 256 + threadIdx.x;
    if (i >= ne) return;
    int pos = atomicAdd(&cursor[dst[i]], 1);
    csr_src[pos] = src[i];
}

// ------------- fused: dot + online softmax + aggregation + elu -----------
// One wave per node; lane = output channel. z_dst row lives in a register;
// each incoming edge gathers its z_src row once (coalesced 256B), dot via
// 6-step butterfly, online-softmax accumulate. Next row prefetched past
// the reduce.
__global__ __launch_bounds__(256) void fused_node(const float* __restrict__ z,
                                                  const int* __restrict__ starts,
                                                  const int* __restrict__ csr_src,
                                                  float* __restrict__ out, int n) {
    int node = blockIdx.x * 4 + (threadIdx.x >> 6);
    if (node >= n) return;
    int lane = threadIdx.x & 63;
    int rs = starts[node], re = starts[node + 1];
    float zd = z[(size_t)node * 64 + lane];

    float m = -INFINITY, denom = 0.f, acc = 0.f;
    for (int c = rs; c < re; c += 64) {
        int j = c + lane;
        int cn = min(64, re - c);
        int sv = j < re ? csr_src[j] : 0;
        int s0 = __shfl(sv, 0);
        float v = z[(size_t)s0 * 64 + lane];          // prefetch row 0
        for (int k = 0; k < cn; k++) {
            float vn = v;
            if (k + 1 < cn) {                          // prefetch next row
                int s1 = __shfl(sv, k + 1);
                vn = z[(size_t)s1 * 64 + lane];
            }
            float p = v * zd;                          // dot via butterfly
#pragma unroll
            for (int mask = 1; mask < 64; mask <<= 1) p += __shfl_xor(p, mask);
            float e = p > 0.f ? p : SLOPE * p;
            if (e > m) {                               // wave-uniform branch
                float sc = __expf(m - e);              // exp(-inf)=0 on first edge
                acc *= sc; denom *= sc; m = e;
            }
            float ex = __expf(e - m);
            denom += ex;
            acc += ex * v;
            v = vn;
        }
    }
    float x = denom > 0.f ? acc / denom : 0.f;
    out[(size_t)node * 64 + lane] = x > 0.f ? x : expm1f(x);
}

// -------------------------------------------------------------- launch ----
extern "C" void kernel_launch(void* const* d_in, const int* in_sizes, int n_in,
                              void* d_out, int out_size, void* d_ws, size_t ws_size,
                              hipStream_t stream) {
    const float* h   = (const float*)d_in[0];
    const float* W   = (const float*)d_in[1];
    const int*   src = (const int*)d_in[2];
    const int*   dst = (const int*)d_in[3];
    int n  = in_sizes[0] / 128;   // 100000
    int ne = in_sizes[2];         // 1600000
    float* out = (float*)d_out;

    float* z       = (float*)d_ws;                    // n*64 floats
    int*   starts  = (int*)(z + (size_t)n * 64);      // n+1 ints
    int*   cursor  = starts + (n + 1);                // n ints (also histogram)
    int*   csr_src = cursor + n;                      // ne ints
    int*   bsums   = csr_src + ne;                    // 32 ints

    int nb_scan = (n + 4095) / 4096;                  // 25

    zero_cnt<<<(n + 255) / 256, 256, 0, stream>>>(cursor, n);
    gemm_kernel<<<(n + 255) / 256, 256, 0, stream>>>(h, W, z, n);
    hist_kernel<<<(ne + 255) / 256, 256, 0, stream>>>(dst, cursor, ne);
    scan1<<<nb_scan, 256, 0, stream>>>(cursor, starts, bsums, n);
    scan2<<<1, 64, 0, stream>>>(bsums, nb_scan, starts, n, ne);
    scan3<<<(n + 255) / 256, 256, 0, stream>>>(starts, cursor, bsums, n);
    scatter_kernel<<<(ne + 255) / 256, 256, 0, stream>>>(src, dst, cursor, csr_src, ne);
    fused_node<<<(n + 3) / 4, 256, 0, stream>>>(z, starts, csr_src, out, n);
}

// Round 7
// 362.993 us; speedup vs baseline: 2.4150x; 1.3390x over previous
//
#include <hip/hip_runtime.h>
#include <math.h>

#define SLOPE 0.2f

// --------------------------------------------------------------- zero ----
__global__ __launch_bounds__(256) void zero_cnt(int* __restrict__ cnt, int n) {
    int i = blockIdx.x * 256 + threadIdx.x;
    if (i < n) cnt[i] = 0;
}

// ---------------------------------------------------------------- gemm ----
// z[node][o] = sum_k h[node][k] * W[o][k];  h:[n][128], W:[64][128], z:[n][64]
// Block = 64 nodes, 256 threads. W transposed into LDS ws[k][o] (pad 68).
// Thread (ng,og) computes a 4-node x 4-out register tile: 64 FMA per
// 8 LDS b128 reads. h read from global (16 threads broadcast per row).
__global__ __launch_bounds__(256) void gemm_kernel(const float* __restrict__ h,
                                                   const float* __restrict__ W,
                                                   float* __restrict__ z, int n) {
    __shared__ float ws[128][68];   // 34.8 KB, transposed W
    int t = threadIdx.x;
    const float4* __restrict__ W4 = reinterpret_cast<const float4*>(W);
#pragma unroll
    for (int j = 0; j < 8; j++) {
        int idx = t + j * 256;            // float4 index into W[64][128]
        float4 w = W4[idx];
        int o = idx >> 5;                 // 0..63
        int k = (idx & 31) << 2;          // 0,4,...,124
        ws[k + 0][o] = w.x; ws[k + 1][o] = w.y;
        ws[k + 2][o] = w.z; ws[k + 3][o] = w.w;
    }
    __syncthreads();

    int nb = blockIdx.x * 64;
    int ng = t >> 4, og = t & 15;
    int n0 = nb + ng * 4;
    if (n0 >= n) return;
    const float* __restrict__ hp = h + (size_t)n0 * 128;

    float acc[4][4] = {};
#pragma unroll 4
    for (int k = 0; k < 128; k += 4) {
        float4 hv[4], wv[4];
#pragma unroll
        for (int i = 0; i < 4; i++) hv[i] = *(const float4*)(hp + i * 128 + k);
#pragma unroll
        for (int kk = 0; kk < 4; kk++) wv[kk] = *(const float4*)&ws[k + kk][og * 4];
#pragma unroll
        for (int i = 0; i < 4; i++) {
            acc[i][0] += hv[i].x * wv[0].x + hv[i].y * wv[1].x + hv[i].z * wv[2].x + hv[i].w * wv[3].x;
            acc[i][1] += hv[i].x * wv[0].y + hv[i].y * wv[1].y + hv[i].z * wv[2].y + hv[i].w * wv[3].y;
            acc[i][2] += hv[i].x * wv[0].z + hv[i].y * wv[1].z + hv[i].z * wv[2].z + hv[i].w * wv[3].z;
            acc[i][3] += hv[i].x * wv[0].w + hv[i].y * wv[1].w + hv[i].z * wv[2].w + hv[i].w * wv[3].w;
        }
    }
#pragma unroll
    for (int i = 0; i < 4; i++) {
        *(float4*)&z[(size_t)(n0 + i) * 64 + og * 4] =
            make_float4(acc[i][0], acc[i][1], acc[i][2], acc[i][3]);
    }
}

// ---------------------------------------------------------- histogram ----
__global__ __launch_bounds__(256) void hist_kernel(const int* __restrict__ dst,
                                                   int* __restrict__ cnt, int ne) {
    int i = blockIdx.x * 256 + threadIdx.x;
    if (i < ne) atomicAdd(&cnt[dst[i]], 1);
}

// ------------------------------------------------- scan (4096/block) -----
__global__ __launch_bounds__(256) void scan1(const int* __restrict__ cnt,
                                             int* __restrict__ starts,
                                             int* __restrict__ bsums, int n) {
    __shared__ int ls[256];
    int tbase = blockIdx.x * 4096 + threadIdx.x * 16;
    int v[16];
    int s = 0;
#pragma unroll
    for (int k = 0; k < 16; k++) {
        int idx = tbase + k;
        int c = idx < n ? cnt[idx] : 0;
        v[k] = c; s += c;
    }
    ls[threadIdx.x] = s;
    __syncthreads();
    for (int off = 1; off < 256; off <<= 1) {
        int t = threadIdx.x >= off ? ls[threadIdx.x - off] : 0;
        __syncthreads();
        ls[threadIdx.x] += t;
        __syncthreads();
    }
    int run = ls[threadIdx.x] - s;   // exclusive prefix of this thread
    if (threadIdx.x == 255) bsums[blockIdx.x] = ls[255];
#pragma unroll
    for (int k = 0; k < 16; k++) {
        int idx = tbase + k;
        if (idx < n) starts[idx] = run;
        run += v[k];
    }
}

__global__ void scan2(int* __restrict__ bsums, int nb, int* __restrict__ starts,
                      int n, int ne) {
    if (threadIdx.x == 0) {
        int run = 0;
        for (int b = 0; b < nb; b++) { int t = bsums[b]; bsums[b] = run; run += t; }
        starts[n] = ne;
    }
}

__global__ __launch_bounds__(256) void scan3(int* __restrict__ starts,
                                             int* __restrict__ cursor,
                                             const int* __restrict__ bsums, int n) {
    int i = blockIdx.x * 256 + threadIdx.x;
    if (i < n) {
        int v = starts[i] + bsums[i >> 12];
        starts[i] = v;
        cursor[i] = v;
    }
}

// -------------------------------------- scatter src indices into CSR -----
__global__ __launch_bounds__(256) void scatter_kernel(const int* __restrict__ src,
                                                      const int* __restrict__ dst,
                                                      int* __restrict__ cursor,
                                                      int* __restrict__ csr_src, int ne) {
    int i = blockIdx.x * 256 + threadIdx.x;
    if (i >= ne) return;
    int pos = atomicAdd(&cursor[dst[i]], 1);
    csr_src[pos] = src[i];
}

// ------------- fused: dot + online softmax + aggregation + elu -----------
// One wave per node; lane = output channel. 4 edges in flight per step:
// 4 independent z_src gathers, interleaved butterflies, batched online-
// softmax rescale (max over the 4, one rescale).
__global__ __launch_bounds__(256) void fused_node(const float* __restrict__ z,
                                                  const int* __restrict__ starts,
                                                  const int* __restrict__ csr_src,
                                                  float* __restrict__ out, int n) {
    int node = blockIdx.x * 4 + (threadIdx.x >> 6);
    if (node >= n) return;
    int lane = threadIdx.x & 63;
    int rs = starts[node], re = starts[node + 1];
    float zd = z[(size_t)node * 64 + lane];

    float m = -INFINITY, denom = 0.f, acc = 0.f;
    for (int c = rs; c < re; c += 64) {
        int j = c + lane;
        int cn = min(64, re - c);
        int sv = j < re ? csr_src[j] : 0;
        int k = 0;
        for (; k + 4 <= cn; k += 4) {
            int s0 = __shfl(sv, k),     s1 = __shfl(sv, k + 1);
            int s2 = __shfl(sv, k + 2), s3 = __shfl(sv, k + 3);
            float v0 = z[(size_t)s0 * 64 + lane];
            float v1 = z[(size_t)s1 * 64 + lane];
            float v2 = z[(size_t)s2 * 64 + lane];
            float v3 = z[(size_t)s3 * 64 + lane];
            float p0 = v0 * zd, p1 = v1 * zd, p2 = v2 * zd, p3 = v3 * zd;
#pragma unroll
            for (int mask = 1; mask < 64; mask <<= 1) {
                p0 += __shfl_xor(p0, mask);
                p1 += __shfl_xor(p1, mask);
                p2 += __shfl_xor(p2, mask);
                p3 += __shfl_xor(p3, mask);
            }
            float e0 = p0 > 0.f ? p0 : SLOPE * p0;
            float e1 = p1 > 0.f ? p1 : SLOPE * p1;
            float e2 = p2 > 0.f ? p2 : SLOPE * p2;
            float e3 = p3 > 0.f ? p3 : SLOPE * p3;
            float mx = fmaxf(fmaxf(e0, e1), fmaxf(e2, e3));
            if (mx > m) {                       // wave-uniform
                float sc = __expf(m - mx);      // first batch: exp(-inf)=0
                acc *= sc; denom *= sc; m = mx;
            }
            float x0 = __expf(e0 - m), x1 = __expf(e1 - m);
            float x2 = __expf(e2 - m), x3 = __expf(e3 - m);
            denom += (x0 + x1) + (x2 + x3);
            acc += x0 * v0 + x1 * v1 + x2 * v2 + x3 * v3;
        }
        for (; k < cn; k++) {
            int s = __shfl(sv, k);
            float v = z[(size_t)s * 64 + lane];
            float p = v * zd;
#pragma unroll
            for (int mask = 1; mask < 64; mask <<= 1) p += __shfl_xor(p, mask);
            float e = p > 0.f ? p : SLOPE * p;
            if (e > m) {
                float sc = __expf(m - e);
                acc *= sc; denom *= sc; m = e;
            }
            float ex = __expf(e - m);
            denom += ex;
            acc += ex * v;
        }
    }
    float x = denom > 0.f ? acc / denom : 0.f;
    out[(size_t)node * 64 + lane] = x > 0.f ? x : expm1f(x);
}

// -------------------------------------------------------------- launch ----
extern "C" void kernel_launch(void* const* d_in, const int* in_sizes, int n_in,
                              void* d_out, int out_size, void* d_ws, size_t ws_size,
                              hipStream_t stream) {
    const float* h   = (const float*)d_in[0];
    const float* W   = (const float*)d_in[1];
    const int*   src = (const int*)d_in[2];
    const int*   dst = (const int*)d_in[3];
    int n  = in_sizes[0] / 128;   // 100000
    int ne = in_sizes[2];         // 1600000
    float* out = (float*)d_out;

    float* z       = (float*)d_ws;                    // n*64 floats
    int*   starts  = (int*)(z + (size_t)n * 64);      // n+1 ints
    int*   cursor  = starts + (n + 1);                // n ints (also histogram)
    int*   csr_src = cursor + n;                      // ne ints
    int*   bsums   = csr_src + ne;                    // 32 ints

    int nb_scan = (n + 4095) / 4096;                  // 25

    zero_cnt<<<(n + 255) / 256, 256, 0, stream>>>(cursor, n);
    gemm_kernel<<<(n + 63) / 64, 256, 0, stream>>>(h, W, z, n);
    hist_kernel<<<(ne + 255) / 256, 256, 0, stream>>>(dst, cursor, ne);
    scan1<<<nb_scan, 256, 0, stream>>>(cursor, starts, bsums, n);
    scan2<<<1, 64, 0, stream>>>(bsums, nb_scan, starts, n, ne);
    scan3<<<(n + 255) / 256, 256, 0, stream>>>(starts, cursor, bsums, n);
    scatter_kernel<<<(ne + 255) / 256, 256, 0, stream>>>(src, dst, cursor, csr_src, ne);
    fused_node<<<(n + 3) / 4, 256, 0, stream>>>(z, starts, csr_src, out, n);
}